// Round 4
// baseline (268.322 us; speedup 1.0000x reference)
//
#include <hip/hip_runtime.h>
#include <hip/hip_bf16.h>

// Gram matrix: G = X @ X^T, X = [512, 65536] fp32, out = [512, 512] fp32.
// Round 14: r12 (dbuf) and r13 (256^2 tile) both REGRESSED vs the plain
// r10 structure. Unifying theory across r1..r13: delivered BW tracks
// per-thread loads-in-flight (Little's law), not tile size or async-ness:
//   r1 reg-staged 8xfloat4/thread  -> 7.9 TB/s;  gload_lds wave-bursts
//   that drain at each barrier     -> 2-5 TB/s.  FETCH ~= 130 MB = one
//   HBM pass (input is LLC-resident) -- we are CONCURRENCY-bound.
// r10's remaining defect was balance: diag blocks ran 64 iters with HALF
// the in-flight loads (4xfloat4) -> 2x critical-path tail. Fix ONLY that:
//   - diag blocks: BK=64, KC=2048, 32 iters, 2 thr/row x 32 floats
//     = 8 float4/thread in flight -- IDENTICAL per-iter MLP and iteration
//     count to upper blocks; every block stages exactly 1 MB.
//   - diag LDS panel [128][68] bf16 (17.4 KB, fits r10's 20.5 KB block);
//     upper panels [128][40] x2 = r10 exact.
//   - loop skeleton, swizzle-free staging, sync pair, epilogue atomics,
//     mirror kernel: byte-for-byte r10. grid 512 = 2 blocks/CU.
// History: r1 fused 135us (7.9 TB/s); r10 sym 100; r11 async 100;
// r12 dbuf 117 (REVERTED); r13 256-tile 126 (REVERTED).

typedef short bf16x8 __attribute__((ext_vector_type(8)));   // 8 bf16 = 4 VGPRs
typedef float f32x4  __attribute__((ext_vector_type(4)));   // MFMA acc

#define HW    65536
#define CDIM  512
#define LDSU  40        // upper panel stride in shorts (r10 proven)
#define LDSD  68        // diag panel stride in shorts (64 + 4 pad)

__device__ __forceinline__ short f2bf(float f) {
    __hip_bfloat16 h = __float2bfloat16(f);   // RNE
    short s;
    __builtin_memcpy(&s, &h, sizeof(short));
    return s;
}

__device__ __forceinline__ bf16x8 cvt8(float4 a, float4 b) {
    bf16x8 v;
    v[0] = f2bf(a.x); v[1] = f2bf(a.y); v[2] = f2bf(a.z); v[3] = f2bf(a.w);
    v[4] = f2bf(b.x); v[5] = f2bf(b.y); v[6] = f2bf(b.z); v[7] = f2bf(b.w);
    return v;
}

__global__ __launch_bounds__(256, 2)
void gram_kernel(const float* __restrict__ X, float* __restrict__ out) {
    // decode: p<128  -> diag tile ti=tj=p>>5, chunk=p&31, KC=2048, BK=64
    //         p>=128 -> upper tile o=(p-128)>>6, chunk=(p-128)&63, KC=1024, BK=32
    // ALL blocks: 32 iterations, 8 float4 loads/thread/iter, 1 MB staged.
    const int p = blockIdx.x;

    // LDS: upper = two [128][40] bf16 panels (20.5 KB, r10 exact);
    //      diag  = one [128][68] bf16 panel (17.4 KB) aliased on top.
    __shared__ short LB[2 * 128 * LDSU];

    const int t    = threadIdx.x;
    const int wave = t >> 6;
    const int lane = t & 63;
    const int wm   = wave & 1;          // 2x2 wave grid, each wave = 64x64
    const int wn   = wave >> 1;
    const int fm   = lane & 15;
    const int kg   = lane >> 4;         // k-group: 8 contiguous bf16

    f32x4 acc[4][4];
#pragma unroll
    for (int i = 0; i < 4; ++i)
#pragma unroll
        for (int j = 0; j < 4; ++j)
            acc[i][j] = (f32x4){0.f, 0.f, 0.f, 0.f};

    int ti, tj;

    if (p < 128) {
        // ---------------- diag path: BK=64, one panel ----------------
        ti = tj = p >> 5;
        const int kbase = (p & 31) << 11;            // *2048
        short* Ds = LB;

        const int srow = t >> 1;                     // 0..127
        const int soff = (t & 1) * 32;               // 32 consecutive floats
        const float* pd = X + (size_t)(ti * 128 + srow) * HW + kbase + soff;
        short* wd = Ds + srow * LDSD + soff;

        int aoff[4], boff[4];
#pragma unroll
        for (int i = 0; i < 4; ++i) {
            aoff[i] = (wm * 64 + i * 16 + fm) * LDSD + kg * 8;
            boff[i] = (wn * 64 + i * 16 + fm) * LDSD + kg * 8;
        }

        for (int it = 0; it < 32; ++it) {
            // 8 float4 in flight per thread (r1's proven MLP)
            float4 a0 = *(const float4*)(pd + 0);
            float4 a1 = *(const float4*)(pd + 4);
            float4 a2 = *(const float4*)(pd + 8);
            float4 a3 = *(const float4*)(pd + 12);
            float4 a4 = *(const float4*)(pd + 16);
            float4 a5 = *(const float4*)(pd + 20);
            float4 a6 = *(const float4*)(pd + 24);
            float4 a7 = *(const float4*)(pd + 28);

            bf16x8 v0 = cvt8(a0, a1), v1 = cvt8(a2, a3);
            bf16x8 v2 = cvt8(a4, a5), v3 = cvt8(a6, a7);

            __syncthreads();   // prior iteration's LDS reads complete
            *(bf16x8*)(wd + 0)  = v0;
            *(bf16x8*)(wd + 8)  = v1;
            *(bf16x8*)(wd + 16) = v2;
            *(bf16x8*)(wd + 24) = v3;
            __syncthreads();   // stage visible to all waves

#pragma unroll
            for (int kk = 0; kk < 2; ++kk) {
                bf16x8 af[4], bfr[4];
#pragma unroll
                for (int i = 0; i < 4; ++i)
                    af[i]  = *(const bf16x8*)(Ds + aoff[i] + kk * 32);
#pragma unroll
                for (int j = 0; j < 4; ++j)
                    bfr[j] = *(const bf16x8*)(Ds + boff[j] + kk * 32);
#pragma unroll
                for (int i = 0; i < 4; ++i)
#pragma unroll
                    for (int j = 0; j < 4; ++j)
                        acc[i][j] = __builtin_amdgcn_mfma_f32_16x16x32_bf16(
                            af[i], bfr[j], acc[i][j], 0, 0, 0);
            }
            pd += 64;
        }
    } else {
        // ---------------- upper path: BK=32, two panels (r10 exact) ----------------
        const int q = p - 128;
        const int o = q >> 6;
        const int TI[6] = {0, 0, 0, 1, 1, 2};
        const int TJ[6] = {1, 2, 3, 2, 3, 3};
        ti = TI[o]; tj = TJ[o];
        const int kbase = (q & 63) << 10;            // *1024
        short* As = LB;
        short* Bs = LB + 128 * LDSU;

        const int srow  = t >> 1;                    // 0..127
        const int shalf = (t & 1) * 16;              // k offset 0 or 16
        const float* pa = X + (size_t)(ti * 128 + srow) * HW + kbase + shalf;
        const float* pb = X + (size_t)(tj * 128 + srow) * HW + kbase + shalf;
        short* wa = As + srow * LDSU + shalf;
        short* wb = Bs + srow * LDSU + shalf;

        int aoff[4], boff[4];
#pragma unroll
        for (int i = 0; i < 4; ++i) {
            aoff[i] = (wm * 64 + i * 16 + fm) * LDSU + kg * 8;
            boff[i] = (wn * 64 + i * 16 + fm) * LDSU + kg * 8;
        }

        for (int it = 0; it < 32; ++it) {
            float4 a0 = *(const float4*)(pa + 0);
            float4 a1 = *(const float4*)(pa + 4);
            float4 a2 = *(const float4*)(pa + 8);
            float4 a3 = *(const float4*)(pa + 12);
            float4 b0 = *(const float4*)(pb + 0);
            float4 b1 = *(const float4*)(pb + 4);
            float4 b2 = *(const float4*)(pb + 8);
            float4 b3 = *(const float4*)(pb + 12);

            bf16x8 va0 = cvt8(a0, a1), va1 = cvt8(a2, a3);
            bf16x8 vb0 = cvt8(b0, b1), vb1 = cvt8(b2, b3);

            __syncthreads();   // prior iteration's LDS reads complete
            *(bf16x8*)(wa + 0) = va0;
            *(bf16x8*)(wa + 8) = va1;
            *(bf16x8*)(wb + 0) = vb0;
            *(bf16x8*)(wb + 8) = vb1;
            __syncthreads();   // stage visible to all waves

            bf16x8 af[4], bfr[4];
#pragma unroll
            for (int i = 0; i < 4; ++i) af[i]  = *(const bf16x8*)(As + aoff[i]);
#pragma unroll
            for (int j = 0; j < 4; ++j) bfr[j] = *(const bf16x8*)(Bs + boff[j]);

#pragma unroll
            for (int i = 0; i < 4; ++i)
#pragma unroll
                for (int j = 0; j < 4; ++j)
                    acc[i][j] = __builtin_amdgcn_mfma_f32_16x16x32_bf16(
                        af[i], bfr[j], acc[i][j], 0, 0, 0);

            pa += 32;
            pb += 32;
        }
    }

    // --- epilogue: row-major coalesced atomics (diag/upper tiles only) ---
    // C/D layout (verified m89/m91): col = lane&15, row = (lane>>4)*4 + reg
    const int orow0 = ti * 128 + wm * 64 + (lane >> 4) * 4;
    const int ocol0 = tj * 128 + wn * 64 + fm;
#pragma unroll
    for (int i = 0; i < 4; ++i)
#pragma unroll
        for (int j = 0; j < 4; ++j)
#pragma unroll
            for (int r = 0; r < 4; ++r)
                atomicAdd(out + (orow0 + i * 16 + r) * CDIM + ocol0 + j * 16,
                          acc[i][j][r]);
}

// ---------------- mirror: copy upper tiles transposed into lower ----------------
__global__ __launch_bounds__(256)
void mirror_kernel(float* __restrict__ out) {
    const int id = blockIdx.x * 256 + threadIdx.x;   // 0..262143
    const int r = id >> 9;
    const int c = id & 511;
    if ((r >> 7) > (c >> 7))          // 128-grain tiles
        out[id] = out[c * CDIM + r];
}

extern "C" void kernel_launch(void* const* d_in, const int* in_sizes, int n_in,
                              void* d_out, int out_size, void* d_ws, size_t ws_size,
                              hipStream_t stream) {
    const float* x = (const float*)d_in[0];
    float* out = (float*)d_out;

    // zero the accumulator (harness poisons d_out with 0xAA before every launch)
    hipMemsetAsync(d_out, 0, (size_t)out_size * sizeof(float), stream);

    gram_kernel<<<dim3(512), dim3(256), 0, stream>>>(x, out);
    mirror_kernel<<<dim3(1024), dim3(256), 0, stream>>>(out);
}

// Round 5
// 246.388 us; speedup vs baseline: 1.0890x; 1.0890x over previous
//
#include <hip/hip_runtime.h>
#include <hip/hip_bf16.h>

// Gram matrix: G = X @ X^T, X = [512, 65536] fp32, out = [512, 512] fp32.
// Round 15: r12 (dbuf), r13 (256^2), r14 (diag BK=64) ALL regressed vs r10.
// Post-mortem fit across rounds: dur_us = gram + ~137us FIXED harness
// overhead (tight 135.9-138.9 spread) -> gram is the only lever.
// Surviving theory for r1's 7.9 TB/s vs symmetric ~5.4: r1 had UNIFORM
// blocks + an oversubscribed grid (backfill queue); r10/r14 have exactly-
// resident grids with heterogeneous diag blocks -> straggler tail on half
// the CUs (measured Occ 17.9% vs nominal 25%).
// Fix: NO diag special path. Every tile (diag included) runs the identical
// two-panel r10 loop; diag blocks just have pb==pa (B-loads are L1 hits of
// the A-loads, LDS double-stage harmless). 10 tiles x 64 chunks (KC=1024,
// BK=32, 32 iters) = grid 640: every block stages 1 MB with the same
// instruction stream; 128-block backfill queue kills the tail. Chunk-major
// tile order spreads concurrent blocks across tiles. Inner loop, LDS
// [128][40] x2, epilogue atomics (10.5M, ~+4us vs r10), mirror: r10 exact.
// History: r1 fused 135us (7.9 TB/s); r10 sym 100; r11 async 100; r12 dbuf
// 117 (REV); r13 256-tile 126 (REV); r14 diag-BK64 131 (REV).

typedef short bf16x8 __attribute__((ext_vector_type(8)));   // 8 bf16 = 4 VGPRs
typedef float f32x4  __attribute__((ext_vector_type(4)));   // MFMA acc

#define HW    65536
#define CDIM  512
#define LDSS  40        // panel stride in shorts (r10 proven)

__device__ __forceinline__ short f2bf(float f) {
    __hip_bfloat16 h = __float2bfloat16(f);   // RNE
    short s;
    __builtin_memcpy(&s, &h, sizeof(short));
    return s;
}

__device__ __forceinline__ bf16x8 cvt8(float4 a, float4 b) {
    bf16x8 v;
    v[0] = f2bf(a.x); v[1] = f2bf(a.y); v[2] = f2bf(a.z); v[3] = f2bf(a.w);
    v[4] = f2bf(b.x); v[5] = f2bf(b.y); v[6] = f2bf(b.z); v[7] = f2bf(b.w);
    return v;
}

__global__ __launch_bounds__(256, 2)
void gram_kernel(const float* __restrict__ X, float* __restrict__ out) {
    // decode: chunk-major so concurrent blocks spread across tiles.
    // p = chunk*10 + tileidx ; tile list = 4 diag + 6 upper, all uniform:
    // KC=1024, BK=32, 32 iters, 1 MB staged, identical instruction stream.
    const int p     = blockIdx.x;        // 0..639
    const int tidx  = p % 10;
    const int chunk = p / 10;            // 0..63
    const int TI[10] = {0, 1, 2, 3, 0, 0, 0, 1, 1, 2};
    const int TJ[10] = {0, 1, 2, 3, 1, 2, 3, 2, 3, 3};
    const int ti = TI[tidx], tj = TJ[tidx];
    const int kbase = chunk << 10;       // *1024

    __shared__ short As[128 * LDSS];
    __shared__ short Bs[128 * LDSS];

    const int t    = threadIdx.x;
    const int wave = t >> 6;
    const int lane = t & 63;
    const int wm   = wave & 1;          // 2x2 wave grid, each wave = 64x64
    const int wn   = wave >> 1;

    // --- staging mapping (r10's): 2 threads per row, 16 consecutive fp32 ---
    const int srow  = t >> 1;           // 0..127
    const int shalf = (t & 1) * 16;     // k offset 0 or 16
    const float* pa = X + (size_t)(ti * 128 + srow) * HW + kbase + shalf;
    const float* pb = X + (size_t)(tj * 128 + srow) * HW + kbase + shalf;
    short* wa = As + srow * LDSS + shalf;
    short* wb = Bs + srow * LDSS + shalf;

    // --- fragment read offsets (A-operand: m = lane&15, k-group = lane>>4) ---
    const int fm = lane & 15;
    const int kg = lane >> 4;           // 0..3, each group = 8 contiguous k
    int a_off[4], b_off[4];
#pragma unroll
    for (int i = 0; i < 4; ++i) {
        a_off[i] = (wm * 64 + i * 16 + fm) * LDSS + kg * 8;
        b_off[i] = (wn * 64 + i * 16 + fm) * LDSS + kg * 8;
    }

    f32x4 acc[4][4];
#pragma unroll
    for (int i = 0; i < 4; ++i)
#pragma unroll
        for (int j = 0; j < 4; ++j)
            acc[i][j] = (f32x4){0.f, 0.f, 0.f, 0.f};

    for (int it = 0; it < 32; ++it) {
        // global fp32 loads: 8 float4/thread in flight for EVERY block
        // (diag blocks: pb==pa, B-loads are back-to-back L1 hits)
        float4 a0 = *(const float4*)(pa + 0);
        float4 a1 = *(const float4*)(pa + 4);
        float4 a2 = *(const float4*)(pa + 8);
        float4 a3 = *(const float4*)(pa + 12);
        float4 b0 = *(const float4*)(pb + 0);
        float4 b1 = *(const float4*)(pb + 4);
        float4 b2 = *(const float4*)(pb + 8);
        float4 b3 = *(const float4*)(pb + 12);

        bf16x8 va0 = cvt8(a0, a1), va1 = cvt8(a2, a3);
        bf16x8 vb0 = cvt8(b0, b1), vb1 = cvt8(b2, b3);

        __syncthreads();   // prior iteration's LDS reads complete
        *(bf16x8*)(wa + 0) = va0;
        *(bf16x8*)(wa + 8) = va1;
        *(bf16x8*)(wb + 0) = vb0;
        *(bf16x8*)(wb + 8) = vb1;
        __syncthreads();   // stage visible to all waves

        bf16x8 af[4], bfr[4];
#pragma unroll
        for (int i = 0; i < 4; ++i) af[i]  = *(const bf16x8*)(As + a_off[i]);
#pragma unroll
        for (int j = 0; j < 4; ++j) bfr[j] = *(const bf16x8*)(Bs + b_off[j]);

#pragma unroll
        for (int i = 0; i < 4; ++i)
#pragma unroll
            for (int j = 0; j < 4; ++j)
                acc[i][j] = __builtin_amdgcn_mfma_f32_16x16x32_bf16(
                    af[i], bfr[j], acc[i][j], 0, 0, 0);

        pa += 32;
        pb += 32;
    }

    // --- epilogue: row-major coalesced atomics (diag/upper tiles only) ---
    // C/D layout (verified m89/m91): col = lane&15, row = (lane>>4)*4 + reg
    const int orow0 = ti * 128 + wm * 64 + (lane >> 4) * 4;
    const int ocol0 = tj * 128 + wn * 64 + fm;
#pragma unroll
    for (int i = 0; i < 4; ++i)
#pragma unroll
        for (int j = 0; j < 4; ++j)
#pragma unroll
            for (int r = 0; r < 4; ++r)
                atomicAdd(out + (orow0 + i * 16 + r) * CDIM + ocol0 + j * 16,
                          acc[i][j][r]);
}

// ---------------- mirror: copy upper tiles transposed into lower ----------------
__global__ __launch_bounds__(256)
void mirror_kernel(float* __restrict__ out) {
    const int id = blockIdx.x * 256 + threadIdx.x;   // 0..262143
    const int r = id >> 9;
    const int c = id & 511;
    if ((r >> 7) > (c >> 7))          // 128-grain tiles
        out[id] = out[c * CDIM + r];
}

extern "C" void kernel_launch(void* const* d_in, const int* in_sizes, int n_in,
                              void* d_out, int out_size, void* d_ws, size_t ws_size,
                              hipStream_t stream) {
    const float* x = (const float*)d_in[0];
    float* out = (float*)d_out;

    // zero the accumulator (harness poisons d_out with 0xAA before every launch)
    hipMemsetAsync(d_out, 0, (size_t)out_size * sizeof(float), stream);

    gram_kernel<<<dim3(640), dim3(256), 0, stream>>>(x, out);
    mirror_kernel<<<dim3(1024), dim3(256), 0, stream>>>(out);
}